// Round 13
// baseline (206.207 us; speedup 1.0000x reference)
//
#include <hip/hip_runtime.h>
#include <math.h>

typedef __bf16 bf16x8 __attribute__((ext_vector_type(8)));
typedef float f32x4 __attribute__((ext_vector_type(4)));
typedef float f32x2 __attribute__((ext_vector_type(2)));
typedef unsigned short u16x8 __attribute__((ext_vector_type(8)));
typedef unsigned short u16x4v __attribute__((ext_vector_type(4)));

constexpr int NIMG = 16384;   // H*W
constexpr int HPITCH = 130;   // padded row pitch (tokens) for g_h

__device__ __forceinline__ unsigned short f2bf(float f){
  unsigned u = __builtin_bit_cast(unsigned, f);
  u += 0x7fffu + ((u>>16)&1u);
  return (unsigned short)(u>>16);
}
__device__ __forceinline__ unsigned pack2(float a, float b){
  return (unsigned)f2bf(a) | ((unsigned)f2bf(b)<<16);
}
__device__ __forceinline__ float bf2f(unsigned short h){
  unsigned u = ((unsigned)h)<<16;
  return __builtin_bit_cast(float, u);
}
__device__ __forceinline__ bf16x8 ldfrag_g(const unsigned short* p){
  u16x8 v = *reinterpret_cast<const u16x8*>(p);
  return __builtin_bit_cast(bf16x8, v);
}
__device__ __forceinline__ f32x4 mfma16(bf16x8 a, bf16x8 b, f32x4 c){
  return __builtin_amdgcn_mfma_f32_16x16x32_bf16(a, b, c, 0, 0, 0);
}

// h-channel permutation: channel c lives at slot c' = (c&15)*16 + (c>>4).
// orig(c') = ((c'&15)<<4) | (c'>>4).  g_h stores fp8-e4m3 (1 B/ch).

// ============ k0: weights fp32 -> bf16 MFMA fragment layout (+ tap repack) ============
__global__ __launch_bounds__(64) void k0_wfrag(
  const float* __restrict__ Wk, const float* __restrict__ Wq,
  const float* __restrict__ Wv, const float* __restrict__ Wr,
  const float* __restrict__ W1, const float* __restrict__ W2,
  const float* __restrict__ dww, const float* __restrict__ dwb,
  float* __restrict__ dwp, unsigned short* __restrict__ wf)
{
  const int bid = blockIdx.x, l = threadIdx.x;
  if (bid == 96){
    // taps+bias keyed by permuted slot PAIR: dwp[cp*24 + j*2 + b] = tap j of
    // orig(2cp+b); dwp[cp*24+18+b] = bias.  (cp = 0..127)
    #pragma unroll
    for (int h=0; h<2; ++h){
      int cp = l + h*64;
      #pragma unroll
      for (int b=0; b<2; ++b){
        int slot = 2*cp + b;
        int f = ((slot&15)<<4) | (slot>>4);
        #pragma unroll
        for (int j=0;j<9;++j) dwp[cp*24 + j*2 + b] = dww[f*9+j];
        dwp[cp*24 + 18 + b] = dwb[f];
        dwp[cp*24 + 20 + b] = 0.f;
        dwp[cp*24 + 22 + b] = 0.f;
      }
    }
    return;
  }
  const float* src; int K, nt, ks; unsigned short* dst; bool perm = false;
  if (bid < 32){
    int w = bid>>3, f = bid&7;
    src = (w==0)?Wk:(w==1)?Wq:(w==2)?Wv:Wr;
    K = 64; nt = f>>1; ks = f&1;
    dst = wf + w*4096 + f*512;
  } else if (bid < 64){
    int f = bid-32; src = W1; K = 64; nt = f>>1; ks = f&1;
    dst = wf + 16384 + f*512;
  } else {
    int f = bid-64; src = W2; K = 256; nt = f>>3; ks = f&7;
    dst = wf + 32768 + f*512; perm = true;   // k index = permuted slot c'
  }
  u16x8 v;
  #pragma unroll
  for (int j=0;j<8;++j){
    int k = ks*32 + (l>>4)*8 + j;
    if (perm) k = ((k&15)<<4) | (k>>4);
    int n = nt*16 + (l&15);
    v[j] = f2bf(src[n*K + k]);
  }
  *reinterpret_cast<u16x8*>(dst + l*8) = v;
}

// ============ zhalo: zero g_h halo columns (fp8) + shared zero-row ============
__global__ __launch_bounds__(256) void zhalo(unsigned* __restrict__ gh, unsigned* __restrict__ zr){
  int idx = blockIdx.x*256 + threadIdx.x;
  if (idx < 262144){
    int ch = idx & 63;           // dword within token (64 dwords = 256 fp8)
    int pos = idx >> 6;
    int side = pos & 1, row = pos >> 1;
    gh[(size_t)(row*HPITCH + side*(HPITCH-1))*64 + ch] = 0;
  } else {
    int j = idx - 262144;
    if (j < 8320) zr[j] = 0;     // 130 tok x 256 fp8 = 8320 dwords
  }
}

// ============ k1: LN1 + K/V proj (MFMA) + ctx accumulation ============
// Grid 1024 (256 tokens/block, 64/wave) for 4 blocks/CU TLP. Reduction
// buffers alias the (dead-by-then) tiles LDS: block LDS = 32 KB.
__global__ __launch_bounds__(256,2) void k1_ctx(
  const float* __restrict__ x, const float* __restrict__ g1, const float* __restrict__ be1,
  const float* __restrict__ bk, const float* __restrict__ bv,
  const unsigned short* __restrict__ wf,
  float* __restrict__ g_part, float* __restrict__ g_sump)
{
  __shared__ unsigned short tiles[4][4096];              // 32 KB
  float* ctx_l  = reinterpret_cast<float*>(&tiles[0][0]);   // 64*68 f32 (aliased)
  float* ssum_l = ctx_l + 64*68;                            // 4*64 f32 (aliased)
  const int t = threadIdx.x, wid = t>>6, l = t&63;
  const int lg = l>>4, l15 = l&15;
  unsigned short* tile = tiles[wid];
  const int tok0 = blockIdx.x*256 + wid*64;

  bf16x8 WkF[8], WvF[8];
  #pragma unroll
  for (int f=0; f<8; ++f){
    WkF[f] = ldfrag_g(wf +    0 + f*512 + l*8);
    WvF[f] = ldfrag_g(wf + 8192 + f*512 + l*8);
  }
  float4 g1v  = *reinterpret_cast<const float4*>(&g1[l15*4]);
  float4 be1v = *reinterpret_cast<const float4*>(&be1[l15*4]);
  float bkv[4], bvv[4];
  #pragma unroll
  for (int ct=0; ct<4; ++ct){ bkv[ct]=bk[ct*16+l15]; bvv[ct]=bv[ct*16+l15]; }

  f32x4 acc[4][4];
  #pragma unroll
  for (int a=0;a<4;++a)
    #pragma unroll
    for (int b=0;b<4;++b) acc[a][b] = (f32x4){0.f,0.f,0.f,0.f};
  float sume[4] = {0.f,0.f,0.f,0.f};

  // ---- LN1 of this wave's 64 tokens -> swizzled bf16 tile ----
  #pragma unroll
  for (int it=0; it<16; ++it){
    int row = it*4 + lg;
    float4 xv = *reinterpret_cast<const float4*>(&x[(size_t)(tok0+row)*64 + l15*4]);
    float s1 = xv.x+xv.y+xv.z+xv.w;
    float s2 = xv.x*xv.x + xv.y*xv.y + xv.z*xv.z + xv.w*xv.w;
    #pragma unroll
    for (int off=1; off<16; off<<=1){ s1 += __shfl_xor(s1,off,64); s2 += __shfl_xor(s2,off,64); }
    float mu = s1*(1.f/64.f);
    float rs = rsqrtf(s2*(1.f/64.f) - mu*mu + 1e-5f);
    uint2 pk = { pack2((xv.x-mu)*rs*g1v.x + be1v.x, (xv.y-mu)*rs*g1v.y + be1v.y),
                 pack2((xv.z-mu)*rs*g1v.z + be1v.z, (xv.w-mu)*rs*g1v.w + be1v.w) };
    *reinterpret_cast<uint2*>(&tile[row*64 + ((l15*4) ^ ((row&7)<<3))]) = pk;
  }
  bf16x8 aF[4][2];
  #pragma unroll
  for (int mt=0;mt<4;++mt){
    int row = mt*16+l15, sw=(row&7)<<3, ab=row*64;
    aF[mt][0] = __builtin_bit_cast(bf16x8, *reinterpret_cast<const u16x8*>(tile+ab+((     lg*8)^sw)));
    aF[mt][1] = __builtin_bit_cast(bf16x8, *reinterpret_cast<const u16x8*>(tile+ab+((32 + lg*8)^sw)));
  }
  #pragma unroll
  for (int half=0; half<2; ++half){
    #pragma unroll
    for (int m2=0;m2<2;++m2){
      const int mt = half*2+m2;
      #pragma unroll
      for (int ct=0;ct<4;++ct){
        f32x4 z = {0.f,0.f,0.f,0.f};
        z = mfma16(aF[mt][0], WkF[ct*2+0], z);
        z = mfma16(aF[mt][1], WkF[ct*2+1], z);
        float e0=__expf(z[0]+bkv[ct]), e1=__expf(z[1]+bkv[ct]);
        float e2=__expf(z[2]+bkv[ct]), e3=__expf(z[3]+bkv[ct]);
        sume[ct] += (e0+e1)+(e2+e3);
        const int c = ct*16+l15, sw = (c&7)<<3;
        const int cb = m2*16+lg*4;
        uint2 pe = { pack2(e0,e1), pack2(e2,e3) };
        *reinterpret_cast<uint2*>(&tile[c*64 + (cb ^ sw)]) = pe;
        f32x4 w = {0.f,0.f,0.f,0.f};
        w = mfma16(aF[mt][0], WvF[ct*2+0], w);
        w = mfma16(aF[mt][1], WvF[ct*2+1], w);
        uint2 pv = { pack2(w[0]+bvv[ct], w[1]+bvv[ct]), pack2(w[2]+bvv[ct], w[3]+bvv[ct]) };
        *reinterpret_cast<uint2*>(&tile[c*64 + ((32+cb) ^ sw)]) = pv;
      }
    }
    bf16x8 eA[4], vB[4];
    #pragma unroll
    for (int cm=0;cm<4;++cm){
      int row = cm*16+l15, sw=(row&7)<<3;
      eA[cm] = __builtin_bit_cast(bf16x8, *reinterpret_cast<const u16x8*>(tile + row*64 + ((     lg*8)^sw)));
      vB[cm] = __builtin_bit_cast(bf16x8, *reinterpret_cast<const u16x8*>(tile + row*64 + ((32 + lg*8)^sw)));
    }
    #pragma unroll
    for (int cm=0; cm<4; ++cm)
      #pragma unroll
      for (int jn=0; jn<4; ++jn)
        acc[cm][jn] = mfma16(eA[cm], vB[jn], acc[cm][jn]);
  }

  // ---- all tile reads done: safe to alias tiles as reduction buffers ----
  __syncthreads();
  #pragma unroll
  for (int ct=0; ct<4; ++ct){
    float s = sume[ct];
    s += __shfl_xor(s,16,64); s += __shfl_xor(s,32,64);
    if (lg==0) ssum_l[wid*64 + ct*16+l15] = s;
  }
  #define CTX_RED(OP) \
    _Pragma("unroll") for (int cm=0;cm<4;++cm) \
    _Pragma("unroll") for (int jn=0;jn<4;++jn) \
    _Pragma("unroll") for (int r=0;r<4;++r) \
      ctx_l[(cm*16+lg*4+r)*68 + jn*16+l15] OP acc[cm][jn][r];
  if (wid==0){ CTX_RED(=) }  __syncthreads();
  if (wid==1){ CTX_RED(+=) } __syncthreads();
  if (wid==2){ CTX_RED(+=) } __syncthreads();
  if (wid==3){ CTX_RED(+=) } __syncthreads();
  #undef CTX_RED
  for (int i=t; i<4096; i+=256)
    g_part[(size_t)blockIdx.x*4096 + i] = ctx_l[(i>>6)*68 + (i&63)];
  if (t<64)
    g_sump[blockIdx.x*64 + t] = ssum_l[t] + ssum_l[64+t] + ssum_l[128+t] + ssum_l[192+t];
}

// ============ k15: reduce 64 partials/img; ctxWr = (ctx_norm @ Wr^T) -> bf16 frags ============
__global__ __launch_bounds__(512) void k15_ctxwr(
  const float* __restrict__ g_part, const float* __restrict__ g_sump,
  const float* __restrict__ Wr, unsigned short* __restrict__ ctxWrF)
{
  __shared__ float sctx[4096];
  __shared__ float sWr[4096];
  __shared__ float sinv[64];
  const int b = blockIdx.x, t = threadIdx.x;
  if (t<64){
    float s=0.f;
    #pragma unroll 8
    for (int p=0;p<64;++p) s += g_sump[(b*64+p)*64 + t];
    sinv[t] = 1.f/s;
  }
  for (int idx=t; idx<4096; idx+=512){
    float s=0.f;
    #pragma unroll 8
    for (int p=0;p<64;++p) s += g_part[(size_t)(b*64+p)*4096 + idx];
    sctx[idx] = s;
  }
  __syncthreads();
  {
    int c = t>>3, d0 = (t&7)*8;
    float invc = sinv[c];
    #pragma unroll
    for (int dd=0; dd<8; ++dd){
      int d = d0+dd; float s = 0.f;
      #pragma unroll
      for (int v=0; v<64; ++v) s += sctx[c*64+v]*Wr[d*64+v];
      sWr[c*64+d] = s*invc;
    }
  }
  __syncthreads();
  {
    int f = t>>6, l = t&63, nt = f>>1, ks = f&1;
    u16x8 v;
    #pragma unroll
    for (int j=0;j<8;++j){
      int k = ks*32 + (l>>4)*8 + j;
      int n = nt*16 + (l&15);
      v[j] = f2bf(sWr[k*64+n]);
    }
    *reinterpret_cast<u16x8*>(ctxWrF + b*4096 + f*512 + l*8) = v;
  }
}

// ============ k2: LN1 + q-softmax + attn + residual + LN2 + W1 -> fp8 g_h ============
__global__ __launch_bounds__(256,2) void k2_attn_ffn1(
  const float* __restrict__ x,
  const float* __restrict__ g1, const float* __restrict__ be1,
  const float* __restrict__ bq, const float* __restrict__ br,
  const float* __restrict__ g2, const float* __restrict__ be2,
  const float* __restrict__ b1,
  const unsigned short* __restrict__ wf,
  const unsigned short* __restrict__ ctxWrF,
  unsigned short* __restrict__ g_txb, unsigned char* __restrict__ g_h)
{
  __shared__ unsigned short tiles[4][4096];
  const int t = threadIdx.x, wid = t>>6, l = t&63;
  const int l15 = l&15, lg = l>>4;
  unsigned short* tile = tiles[wid];
  const int tok0 = (blockIdx.x*4 + wid)*64;
  const int img  = blockIdx.x>>6;
  const int yrow = (tok0>>7)&127;
  const int xb   = tok0&127;
  const size_t hbase = ((size_t)(img*128 + yrow)*HPITCH + 1 + xb)*256;  // BYTES (fp8)

  bf16x8 WqF[8], CWF[8];
  #pragma unroll
  for (int f=0; f<8; ++f){
    WqF[f] = ldfrag_g(wf + 4096 + f*512 + l*8);
    CWF[f] = ldfrag_g(ctxWrF + img*4096 + f*512 + l*8);
  }
  float4 g1v  = *reinterpret_cast<const float4*>(&g1[l15*4]);
  float4 be1v = *reinterpret_cast<const float4*>(&be1[l15*4]);
  float bqv[4], brv[4], g2v[4], be2v[4];
  #pragma unroll
  for (int nt=0; nt<4; ++nt){
    bqv[nt]=bq[nt*16+l15]; brv[nt]=br[nt*16+l15];
    g2v[nt]=g2[nt*16+l15]; be2v[nt]=be2[nt*16+l15];
  }
  float b1v[16];
  #pragma unroll
  for (int i=0;i<16;++i) b1v[i]=b1[i*16+l15];

  // ---- LN1 -> swizzled bf16 tile ----
  #pragma unroll
  for (int it=0; it<16; ++it){
    int row = it*4 + lg;
    float4 xv = *reinterpret_cast<const float4*>(&x[(size_t)(tok0+row)*64 + l15*4]);
    float s1 = xv.x+xv.y+xv.z+xv.w;
    float s2 = xv.x*xv.x + xv.y*xv.y + xv.z*xv.z + xv.w*xv.w;
    #pragma unroll
    for (int off=1; off<16; off<<=1){ s1 += __shfl_xor(s1,off,64); s2 += __shfl_xor(s2,off,64); }
    float mu = s1*(1.f/64.f);
    float rs = rsqrtf(s2*(1.f/64.f) - mu*mu + 1e-5f);
    uint2 pk = { pack2((xv.x-mu)*rs*g1v.x + be1v.x, (xv.y-mu)*rs*g1v.y + be1v.y),
                 pack2((xv.z-mu)*rs*g1v.z + be1v.z, (xv.w-mu)*rs*g1v.w + be1v.w) };
    *reinterpret_cast<uint2*>(&tile[row*64 + ((l15*4) ^ ((row&7)<<3))]) = pk;
  }

  // ---- phase A: per m-tile attn chain; leaves n2 in the tile ----
  for (int mt=0; mt<4; ++mt){
    const int arow = mt*16 + l15;
    const int asw  = (arow&7)<<3;
    const int abase= arow*64;
    bf16x8 a0 = __builtin_bit_cast(bf16x8, *reinterpret_cast<const u16x8*>(tile + abase + ((     lg*8) ^ asw)));
    bf16x8 a1 = __builtin_bit_cast(bf16x8, *reinterpret_cast<const u16x8*>(tile + abase + ((32 + lg*8) ^ asw)));
    f32x4 qa[4];
    #pragma unroll
    for (int nt=0; nt<4; ++nt){
      f32x4 z = {0.f,0.f,0.f,0.f};
      z = mfma16(a0, WqF[nt*2+0], z);
      z = mfma16(a1, WqF[nt*2+1], z);
      qa[nt] = z;
    }
    #pragma unroll
    for (int nt=0; nt<4; ++nt)
      #pragma unroll
      for (int r=0; r<4; ++r) qa[nt][r] += bqv[nt];
    float mx[4];
    #pragma unroll
    for (int r=0;r<4;++r) mx[r] = fmaxf(fmaxf(qa[0][r],qa[1][r]), fmaxf(qa[2][r],qa[3][r]));
    #pragma unroll
    for (int off=1; off<16; off<<=1)
      #pragma unroll
      for (int r=0;r<4;++r) mx[r] = fmaxf(mx[r], __shfl_xor(mx[r], off, 64));
    float sm[4] = {0.f,0.f,0.f,0.f};
    #pragma unroll
    for (int nt=0;nt<4;++nt)
      #pragma unroll
      for (int r=0;r<4;++r){ float e = __expf(qa[nt][r]-mx[r]); qa[nt][r]=e; sm[r]+=e; }
    #pragma unroll
    for (int off=1; off<16; off<<=1)
      #pragma unroll
      for (int r=0;r<4;++r) sm[r] += __shfl_xor(sm[r], off, 64);
    float inv[4];
    #pragma unroll
    for (int r=0;r<4;++r) inv[r] = 1.f/sm[r];
    #pragma unroll
    for (int nt=0;nt<4;++nt)
      #pragma unroll
      for (int r=0;r<4;++r){
        int row = mt*16 + lg*4 + r, col = nt*16 + l15;
        tile[row*64 + (col ^ ((row&7)<<3))] = f2bf(qa[nt][r]*inv[r]);
      }
    bf16x8 p0 = __builtin_bit_cast(bf16x8, *reinterpret_cast<const u16x8*>(tile + abase + ((     lg*8) ^ asw)));
    bf16x8 p1 = __builtin_bit_cast(bf16x8, *reinterpret_cast<const u16x8*>(tile + abase + ((32 + lg*8) ^ asw)));
    f32x4 ao[4];
    #pragma unroll
    for (int nt=0; nt<4; ++nt){
      f32x4 z = {0.f,0.f,0.f,0.f};
      z = mfma16(p0, CWF[nt*2+0], z);
      z = mfma16(p1, CWF[nt*2+1], z);
      ao[nt] = z;
    }
    float txv[4][4];
    float s1v[4] = {0.f,0.f,0.f,0.f}, s2v[4] = {0.f,0.f,0.f,0.f};
    #pragma unroll
    for (int nt=0;nt<4;++nt)
      #pragma unroll
      for (int r=0;r<4;++r){
        size_t row = (size_t)(tok0 + mt*16 + lg*4 + r);
        float v = ao[nt][r] + brv[nt] + x[row*64 + nt*16+l15];
        g_txb[row*64 + nt*16+l15] = f2bf(v);
        txv[nt][r] = v; s1v[r] += v; s2v[r] += v*v;
      }
    #pragma unroll
    for (int off=1; off<16; off<<=1)
      #pragma unroll
      for (int r=0;r<4;++r){ s1v[r] += __shfl_xor(s1v[r], off, 64); s2v[r] += __shfl_xor(s2v[r], off, 64); }
    #pragma unroll
    for (int r=0;r<4;++r){
      float mu2 = s1v[r]*(1.f/64.f);
      float rs  = rsqrtf(s2v[r]*(1.f/64.f) - mu2*mu2 + 1e-5f);
      s1v[r] = mu2; s2v[r] = rs;
    }
    #pragma unroll
    for (int nt=0;nt<4;++nt)
      #pragma unroll
      for (int r=0;r<4;++r){
        int row = mt*16 + lg*4 + r, col = nt*16 + l15;
        float n2 = (txv[nt][r]-s1v[r])*s2v[r]*g2v[nt] + be2v[nt];
        tile[row*64 + (col ^ ((row&7)<<3))] = f2bf(n2);
      }
  }

  // ---- phase B: h = n2 @ W1^T + b1; mt-outer, fp8-packed PERMUTED uint4 stores ----
  // channel c = nt2*16 + l15 stored at slot c' = l15*16 + nt2  => 16 contiguous fp8/thread/row.
  for (int mt=0; mt<4; ++mt){
    const int arow = mt*16 + l15;
    const int asw  = (arow&7)<<3;
    const int abase= arow*64;
    bf16x8 n20 = __builtin_bit_cast(bf16x8, *reinterpret_cast<const u16x8*>(tile + abase + ((     lg*8) ^ asw)));
    bf16x8 n21 = __builtin_bit_cast(bf16x8, *reinterpret_cast<const u16x8*>(tile + abase + ((32 + lg*8) ^ asw)));
    unsigned hq[4][4];
    #pragma unroll
    for (int np=0; np<8; ++np){
      bf16x8 wa0 = ldfrag_g(wf + 16384 + (np*4+0)*512 + l*8);
      bf16x8 wa1 = ldfrag_g(wf + 16384 + (np*4+1)*512 + l*8);
      bf16x8 wb0 = ldfrag_g(wf + 16384 + (np*4+2)*512 + l*8);
      bf16x8 wb1 = ldfrag_g(wf + 16384 + (np*4+3)*512 + l*8);
      float ba = b1v[np*2], bb = b1v[np*2+1];
      f32x4 ha = {ba,ba,ba,ba};
      ha = mfma16(n20, wa0, ha);
      ha = mfma16(n21, wa1, ha);
      f32x4 hb = {bb,bb,bb,bb};
      hb = mfma16(n20, wb0, hb);
      hb = mfma16(n21, wb1, hb);
      const int d = np>>1;
      if ((np&1)==0){
        #pragma unroll
        for (int r=0;r<4;++r)
          hq[r][d] = (unsigned)__builtin_amdgcn_cvt_pk_fp8_f32(ha[r], hb[r], 0, false);
      } else {
        #pragma unroll
        for (int r=0;r<4;++r)
          hq[r][d] = (unsigned)__builtin_amdgcn_cvt_pk_fp8_f32(ha[r], hb[r], (int)hq[r][d], true);
      }
    }
    #pragma unroll
    for (int r=0;r<4;++r){
      const size_t ro = hbase + (size_t)(mt*16+lg*4+r)*256 + l15*16;
      uint4 v = { hq[r][0], hq[r][1], hq[r][2], hq[r][3] };
      *reinterpret_cast<uint4*>(g_h + ro) = v;
    }
  }
}

// ============ k3: depthwise conv3x3 + GELU + W2 — fp8 ring, 2ch/lane packed conv ============
// Block = 16 x-tok x 8 y-rows (grid 2048): 2 scheduling rounds/CU to overlap
// inter-block skew. Staging map pi=1+(t>>4), c0=(t&15)*16.
__global__ __launch_bounds__(256,4) void k3_conv_ffn2(
  const unsigned char* __restrict__ g_h,
  const unsigned char* __restrict__ zrow,
  const float* __restrict__ dwp,
  const float* __restrict__ b2,
  const unsigned short* __restrict__ wf,
  const unsigned short* __restrict__ g_txb, float* __restrict__ out)
{
  __shared__ unsigned ring[4][1170];        // 4 slots x 18 pos x 65-dword pitch = 18.7 KB
  __shared__ unsigned short obuf[2][4096];  // double-buffered 16tok x 256ch = 16 KB
  const int t = threadIdx.x, w = t>>6, l = t&63;
  const int l15 = l&15, lg = l>>4;
  const int bid = (blockIdx.x & 7)*256 + (blockIdx.x >> 3);   // XCD-chunked remap (2048)
  const int img = bid>>7;
  const int r7  = bid&127;
  const int y0  = (r7>>3)*8, x0 = (r7&7)*16;

  // conv: lane's channel pair cp (slots 2cp, 2cp+1); position group pg
  const int cp = t & 127;
  const int pg = t >> 7;
  f32x2 tp[9];
  #pragma unroll
  for (int j=0;j<9;++j)
    tp[j] = *reinterpret_cast<const f32x2*>(&dwp[cp*24 + j*2]);
  const f32x2 cb2 = *reinterpret_cast<const f32x2*>(&dwp[cp*24 + 18]);

  // W2 frags for output quarter ntc = w
  bf16x8 W2F[8];
  #pragma unroll
  for (int q=0;q<8;++q)
    W2F[q] = ldfrag_g(wf + 32768 + (w*8 + q)*512 + l*8);
  const float4 b2q = *reinterpret_cast<const float4*>(&b2[w*16 + lg*4]);

  // staging map: thread t stages position pi = 1+(t>>4), channels c0..c0+15
  const int pi = 1 + (t>>4);
  const int c0 = (t&15)*16;

  auto rowsrc = [&](int ri) -> const unsigned char* {
    return (ri>=0 && ri<128)
      ? g_h + ((size_t)(img*128+ri)*HPITCH + x0)*256
      : zrow + x0*256;
  };
  auto ldrow = [&](int ri, uint4* m, unsigned* h){
    const unsigned char* src = rowsrc(ri);
    *m = *reinterpret_cast<const uint4*>(src + pi*256 + c0);
    if (t < 128){
      int ph = (t<64)?0:17, dh = t&63;
      *h = reinterpret_cast<const unsigned*>(src + ph*256)[dh];
    }
  };
  auto wrrow = [&](int sl, uint4 m, unsigned h){
    unsigned* rg = ring[sl];
    const int base = pi*65 + (c0>>2);
    rg[base+0] = m.x; rg[base+1] = m.y; rg[base+2] = m.z; rg[base+3] = m.w;
    if (t < 128){
      int ph = (t<64)?0:17, dh = t&63;
      rg[ph*65 + dh] = h;
    }
  };

  // prologue: stage rows y0-1, y0, y0+1 into slots 0,1,2
  {
    uint4 m0,m1,m2; unsigned h0=0,h1=0,h2=0;
    ldrow(y0-1,&m0,&h0); ldrow(y0,&m1,&h1); ldrow(y0+1,&m2,&h2);
    wrrow(0,m0,h0); wrrow(1,m1,h1); wrrow(2,m2,h2);
  }
  __syncthreads();

  const f32x2 kC0 = {-2.3022082f,-2.3022082f};
  const f32x2 kC1 = {-0.1029432f,-0.1029432f};

  for (int yy=0; yy<8; ++yy){
    const int gy = y0 + yy;
    // T14 issue-early: fp8 loads of row gy+2 into regs
    uint4 rm; unsigned rh = 0;
    ldrow(gy+2, &rm, &rh);
    // epilogue residual prefetch
    const size_t gtok = (size_t)img*16384 + (size_t)gy*128 + x0 + l15;
    const u16x4v tq = *reinterpret_cast<const u16x4v*>(&g_txb[gtok*64 + w*16 + lg*4]);

    // conv from fp8 ring (rows y-1,y,y+1 = slots yy, yy+1, yy+2 mod 4)
    {
      const unsigned short* rA = reinterpret_cast<const unsigned short*>(ring[(yy  )&3]);
      const unsigned short* rB = reinterpret_cast<const unsigned short*>(ring[(yy+1)&3]);
      const unsigned short* rC = reinterpret_cast<const unsigned short*>(ring[(yy+2)&3]);
      unsigned short* ob = obuf[yy&1];
      const int rb = pg*8;
      f32x2 PA = __builtin_amdgcn_cvt_pk_f32_fp8((int)rA[(rb  )*130 + cp], false);
      f32x2 PB = __builtin_amdgcn_cvt_pk_f32_fp8((int)rB[(rb  )*130 + cp], false);
      f32x2 PC = __builtin_amdgcn_cvt_pk_f32_fp8((int)rC[(rb  )*130 + cp], false);
      f32x2 CA = __builtin_amdgcn_cvt_pk_f32_fp8((int)rA[(rb+1)*130 + cp], false);
      f32x2 CB = __builtin_amdgcn_cvt_pk_f32_fp8((int)rB[(rb+1)*130 + cp], false);
      f32x2 CC = __builtin_amdgcn_cvt_pk_f32_fp8((int)rC[(rb+1)*130 + cp], false);
      #pragma unroll
      for (int i=0;i<8;++i){
        const int ro = (rb+i+2)*130 + cp;
        f32x2 NA = __builtin_amdgcn_cvt_pk_f32_fp8((int)rA[ro], false);
        f32x2 NB = __builtin_amdgcn_cvt_pk_f32_fp8((int)rB[ro], false);
        f32x2 NC = __builtin_amdgcn_cvt_pk_f32_fp8((int)rC[ro], false);
        f32x2 a = cb2;
        a += tp[0]*PA; a += tp[1]*CA; a += tp[2]*NA;
        a += tp[3]*PB; a += tp[4]*CB; a += tp[5]*NB;
        a += tp[6]*PC; a += tp[7]*CC; a += tp[8]*NC;
        f32x2 u = a*a;
        f32x2 wv = u*kC1 + kC0;
        f32x2 arg = a*wv;
        f32x2 e;
        e[0]=__builtin_amdgcn_exp2f(arg[0]); e[1]=__builtin_amdgcn_exp2f(arg[1]);
        f32x2 den = e + (f32x2){1.f,1.f};
        f32x2 rc;
        rc[0]=__builtin_amdgcn_rcpf(den[0]); rc[1]=__builtin_amdgcn_rcpf(den[1]);
        f32x2 g = a*rc;
        unsigned pk;
        asm("v_cvt_pk_bf16_f32 %0, %1, %2" : "=v"(pk) : "v"(g[0]), "v"(g[1]));
        const int p = rb + i;
        *reinterpret_cast<unsigned*>(&ob[p*256 + ((2*cp) ^ ((p&7)<<3))]) = pk;
        PA=CA; PB=CB; PC=CC; CA=NA; CB=NB; CC=NC;
      }
    }

    // write-late: staged fp8 row -> ring slot (yy+3)&3 (raw dwords)
    wrrow((yy+3)&3, rm, rh);
    __syncthreads();

    // W2 MFMA: wave w computes output quarter w over K=256
    f32x4 oacc = {0.f,0.f,0.f,0.f};
    const int nsw = (l15&7)<<3;
    const unsigned short* ob = obuf[yy&1];
    #pragma unroll
    for (int i=0;i<4;++i){
      bf16x8 fb0 = __builtin_bit_cast(bf16x8,
        *reinterpret_cast<const u16x8*>(&ob[l15*256 + ((i*64      + lg*8) ^ nsw)]));
      bf16x8 fb1 = __builtin_bit_cast(bf16x8,
        *reinterpret_cast<const u16x8*>(&ob[l15*256 + ((i*64 + 32 + lg*8) ^ nsw)]));
      oacc = mfma16(W2F[i*2+0], fb0, oacc);
      oacc = mfma16(W2F[i*2+1], fb1, oacc);
    }
    float4 o;
    o.x = oacc[0] + b2q.x + bf2f(tq[0]);
    o.y = oacc[1] + b2q.y + bf2f(tq[1]);
    o.z = oacc[2] + b2q.z + bf2f(tq[2]);
    o.w = oacc[3] + b2q.w + bf2f(tq[3]);
    *reinterpret_cast<float4*>(&out[gtok*64 + w*16 + lg*4]) = o;
  }
}

extern "C" void kernel_launch(void* const* d_in, const int* in_sizes, int n_in,
                              void* d_out, int out_size, void* d_ws, size_t ws_size,
                              hipStream_t stream)
{
  const float* x  =(const float*)d_in[0];
  const float* g1 =(const float*)d_in[3];
  const float* be1=(const float*)d_in[4];
  const float* Wk =(const float*)d_in[5];
  const float* bk =(const float*)d_in[6];
  const float* Wq =(const float*)d_in[7];
  const float* bq =(const float*)d_in[8];
  const float* Wv =(const float*)d_in[9];
  const float* bv =(const float*)d_in[10];
  const float* Wr =(const float*)d_in[11];
  const float* br =(const float*)d_in[12];
  const float* g2 =(const float*)d_in[13];
  const float* be2=(const float*)d_in[14];
  const float* W1 =(const float*)d_in[15];
  const float* b1 =(const float*)d_in[16];
  const float* dww=(const float*)d_in[17];
  const float* dwb=(const float*)d_in[18];
  const float* W2 =(const float*)d_in[19];
  const float* b2 =(const float*)d_in[20];
  float* outp = (float*)d_out;
  char* ws = (char*)d_ws;

  unsigned short* wfb    = (unsigned short*)ws;                 // 96KB
  unsigned short* ctxWrF = (unsigned short*)(ws + 98304);       // 128KB
  float* g_sump = (float*)(ws + 229376);                        // 256KB (1024x64 f32)
  float* g_part = (float*)(ws + 524288);                        // 16.78MB (1024x4096 f32)
  unsigned short* g_txb = (unsigned short*)(ws + 17825792);     // 32MB bf16
  unsigned char* g_h    = (unsigned char*)(ws + 51380224);      // 68.2MB padded fp8
  unsigned char* zr     = (unsigned char*)(ws + 119537664);     // 33KB fp8 zero row
  float* dwp            = (float*)(ws + 119603200);             // 12KB repacked taps+bias

  hipLaunchKernelGGL(k0_wfrag, dim3(97), dim3(64), 0, stream, Wk, Wq, Wv, Wr, W1, W2, dww, dwb, dwp, wfb);
  hipLaunchKernelGGL(zhalo, dim3(1057), dim3(256), 0, stream, (unsigned*)g_h, (unsigned*)zr);
  hipLaunchKernelGGL(k1_ctx, dim3(1024), dim3(256), 0, stream, x, g1, be1, bk, bv, wfb, g_part, g_sump);
  hipLaunchKernelGGL(k15_ctxwr, dim3(16), dim3(512), 0, stream, g_part, g_sump, Wr, ctxWrF);
  hipLaunchKernelGGL(k2_attn_ffn1, dim3(1024), dim3(256), 0, stream,
                     x, g1, be1, bq, br, g2, be2, b1, wfb, ctxWrF, g_txb, g_h);
  hipLaunchKernelGGL(k3_conv_ffn2, dim3(2048), dim3(256), 0, stream,
                     g_h, zr, dwp, b2, wfb, g_txb, outp);
}

// Round 14
// 203.239 us; speedup vs baseline: 1.0146x; 1.0146x over previous
//
#include <hip/hip_runtime.h>
#include <math.h>

typedef __bf16 bf16x8 __attribute__((ext_vector_type(8)));
typedef float f32x4 __attribute__((ext_vector_type(4)));
typedef float f32x2 __attribute__((ext_vector_type(2)));
typedef unsigned short u16x8 __attribute__((ext_vector_type(8)));
typedef unsigned short u16x4v __attribute__((ext_vector_type(4)));

constexpr int NIMG = 16384;   // H*W
constexpr int HPITCH = 130;   // padded row pitch (tokens) for g_h

__device__ __forceinline__ unsigned short f2bf(float f){
  unsigned u = __builtin_bit_cast(unsigned, f);
  u += 0x7fffu + ((u>>16)&1u);
  return (unsigned short)(u>>16);
}
__device__ __forceinline__ unsigned pack2(float a, float b){
  return (unsigned)f2bf(a) | ((unsigned)f2bf(b)<<16);
}
__device__ __forceinline__ float bf2f(unsigned short h){
  unsigned u = ((unsigned)h)<<16;
  return __builtin_bit_cast(float, u);
}
__device__ __forceinline__ bf16x8 ldfrag_g(const unsigned short* p){
  u16x8 v = *reinterpret_cast<const u16x8*>(p);
  return __builtin_bit_cast(bf16x8, v);
}
__device__ __forceinline__ f32x4 mfma16(bf16x8 a, bf16x8 b, f32x4 c){
  return __builtin_amdgcn_mfma_f32_16x16x32_bf16(a, b, c, 0, 0, 0);
}

// h-channel permutation: channel c lives at slot c' = (c&15)*16 + (c>>4).
// orig(c') = ((c'&15)<<4) | (c'>>4).  g_h stores fp8-e4m3 (1 B/ch).

// ============ k0: weights fp32 -> bf16 MFMA fragment layout (+ tap repack) ============
__global__ __launch_bounds__(64) void k0_wfrag(
  const float* __restrict__ Wk, const float* __restrict__ Wq,
  const float* __restrict__ Wv, const float* __restrict__ Wr,
  const float* __restrict__ W1, const float* __restrict__ W2,
  const float* __restrict__ dww, const float* __restrict__ dwb,
  float* __restrict__ dwp, unsigned short* __restrict__ wf)
{
  const int bid = blockIdx.x, l = threadIdx.x;
  if (bid == 96){
    // taps+bias keyed by permuted slot PAIR: dwp[cp*24 + j*2 + b] = tap j of
    // orig(2cp+b); dwp[cp*24+18+b] = bias.  (cp = 0..127)
    #pragma unroll
    for (int h=0; h<2; ++h){
      int cp = l + h*64;
      #pragma unroll
      for (int b=0; b<2; ++b){
        int slot = 2*cp + b;
        int f = ((slot&15)<<4) | (slot>>4);
        #pragma unroll
        for (int j=0;j<9;++j) dwp[cp*24 + j*2 + b] = dww[f*9+j];
        dwp[cp*24 + 18 + b] = dwb[f];
        dwp[cp*24 + 20 + b] = 0.f;
        dwp[cp*24 + 22 + b] = 0.f;
      }
    }
    return;
  }
  const float* src; int K, nt, ks; unsigned short* dst; bool perm = false;
  if (bid < 32){
    int w = bid>>3, f = bid&7;
    src = (w==0)?Wk:(w==1)?Wq:(w==2)?Wv:Wr;
    K = 64; nt = f>>1; ks = f&1;
    dst = wf + w*4096 + f*512;
  } else if (bid < 64){
    int f = bid-32; src = W1; K = 64; nt = f>>1; ks = f&1;
    dst = wf + 16384 + f*512;
  } else {
    int f = bid-64; src = W2; K = 256; nt = f>>3; ks = f&7;
    dst = wf + 32768 + f*512; perm = true;   // k index = permuted slot c'
  }
  u16x8 v;
  #pragma unroll
  for (int j=0;j<8;++j){
    int k = ks*32 + (l>>4)*8 + j;
    if (perm) k = ((k&15)<<4) | (k>>4);
    int n = nt*16 + (l&15);
    v[j] = f2bf(src[n*K + k]);
  }
  *reinterpret_cast<u16x8*>(dst + l*8) = v;
}

// ============ zhalo: zero g_h halo columns (fp8) + shared zero-row ============
__global__ __launch_bounds__(256) void zhalo(unsigned* __restrict__ gh, unsigned* __restrict__ zr){
  int idx = blockIdx.x*256 + threadIdx.x;
  if (idx < 262144){
    int ch = idx & 63;           // dword within token (64 dwords = 256 fp8)
    int pos = idx >> 6;
    int side = pos & 1, row = pos >> 1;
    gh[(size_t)(row*HPITCH + side*(HPITCH-1))*64 + ch] = 0;
  } else {
    int j = idx - 262144;
    if (j < 8320) zr[j] = 0;     // 130 tok x 256 fp8 = 8320 dwords
  }
}

// ============ k1: LN1 + K/V proj (MFMA) + ctx accumulation ============
// Grid 1024 (256 tokens/block, 64/wave) for 4 blocks/CU TLP. Reduction
// buffers alias the (dead-by-then) tiles LDS: block LDS = 32 KB.
__global__ __launch_bounds__(256,2) void k1_ctx(
  const float* __restrict__ x, const float* __restrict__ g1, const float* __restrict__ be1,
  const float* __restrict__ bk, const float* __restrict__ bv,
  const unsigned short* __restrict__ wf,
  float* __restrict__ g_part, float* __restrict__ g_sump)
{
  __shared__ unsigned short tiles[4][4096];              // 32 KB
  float* ctx_l  = reinterpret_cast<float*>(&tiles[0][0]);   // 64*68 f32 (aliased)
  float* ssum_l = ctx_l + 64*68;                            // 4*64 f32 (aliased)
  const int t = threadIdx.x, wid = t>>6, l = t&63;
  const int lg = l>>4, l15 = l&15;
  unsigned short* tile = tiles[wid];
  const int tok0 = blockIdx.x*256 + wid*64;

  bf16x8 WkF[8], WvF[8];
  #pragma unroll
  for (int f=0; f<8; ++f){
    WkF[f] = ldfrag_g(wf +    0 + f*512 + l*8);
    WvF[f] = ldfrag_g(wf + 8192 + f*512 + l*8);
  }
  float4 g1v  = *reinterpret_cast<const float4*>(&g1[l15*4]);
  float4 be1v = *reinterpret_cast<const float4*>(&be1[l15*4]);
  float bkv[4], bvv[4];
  #pragma unroll
  for (int ct=0; ct<4; ++ct){ bkv[ct]=bk[ct*16+l15]; bvv[ct]=bv[ct*16+l15]; }

  f32x4 acc[4][4];
  #pragma unroll
  for (int a=0;a<4;++a)
    #pragma unroll
    for (int b=0;b<4;++b) acc[a][b] = (f32x4){0.f,0.f,0.f,0.f};
  float sume[4] = {0.f,0.f,0.f,0.f};

  // ---- LN1 of this wave's 64 tokens -> swizzled bf16 tile ----
  #pragma unroll
  for (int it=0; it<16; ++it){
    int row = it*4 + lg;
    float4 xv = *reinterpret_cast<const float4*>(&x[(size_t)(tok0+row)*64 + l15*4]);
    float s1 = xv.x+xv.y+xv.z+xv.w;
    float s2 = xv.x*xv.x + xv.y*xv.y + xv.z*xv.z + xv.w*xv.w;
    #pragma unroll
    for (int off=1; off<16; off<<=1){ s1 += __shfl_xor(s1,off,64); s2 += __shfl_xor(s2,off,64); }
    float mu = s1*(1.f/64.f);
    float rs = rsqrtf(s2*(1.f/64.f) - mu*mu + 1e-5f);
    uint2 pk = { pack2((xv.x-mu)*rs*g1v.x + be1v.x, (xv.y-mu)*rs*g1v.y + be1v.y),
                 pack2((xv.z-mu)*rs*g1v.z + be1v.z, (xv.w-mu)*rs*g1v.w + be1v.w) };
    *reinterpret_cast<uint2*>(&tile[row*64 + ((l15*4) ^ ((row&7)<<3))]) = pk;
  }
  bf16x8 aF[4][2];
  #pragma unroll
  for (int mt=0;mt<4;++mt){
    int row = mt*16+l15, sw=(row&7)<<3, ab=row*64;
    aF[mt][0] = __builtin_bit_cast(bf16x8, *reinterpret_cast<const u16x8*>(tile+ab+((     lg*8)^sw)));
    aF[mt][1] = __builtin_bit_cast(bf16x8, *reinterpret_cast<const u16x8*>(tile+ab+((32 + lg*8)^sw)));
  }
  #pragma unroll
  for (int half=0; half<2; ++half){
    #pragma unroll
    for (int m2=0;m2<2;++m2){
      const int mt = half*2+m2;
      #pragma unroll
      for (int ct=0;ct<4;++ct){
        f32x4 z = {0.f,0.f,0.f,0.f};
        z = mfma16(aF[mt][0], WkF[ct*2+0], z);
        z = mfma16(aF[mt][1], WkF[ct*2+1], z);
        float e0=__expf(z[0]+bkv[ct]), e1=__expf(z[1]+bkv[ct]);
        float e2=__expf(z[2]+bkv[ct]), e3=__expf(z[3]+bkv[ct]);
        sume[ct] += (e0+e1)+(e2+e3);
        const int c = ct*16+l15, sw = (c&7)<<3;
        const int cb = m2*16+lg*4;
        uint2 pe = { pack2(e0,e1), pack2(e2,e3) };
        *reinterpret_cast<uint2*>(&tile[c*64 + (cb ^ sw)]) = pe;
        f32x4 w = {0.f,0.f,0.f,0.f};
        w = mfma16(aF[mt][0], WvF[ct*2+0], w);
        w = mfma16(aF[mt][1], WvF[ct*2+1], w);
        uint2 pv = { pack2(w[0]+bvv[ct], w[1]+bvv[ct]), pack2(w[2]+bvv[ct], w[3]+bvv[ct]) };
        *reinterpret_cast<uint2*>(&tile[c*64 + ((32+cb) ^ sw)]) = pv;
      }
    }
    bf16x8 eA[4], vB[4];
    #pragma unroll
    for (int cm=0;cm<4;++cm){
      int row = cm*16+l15, sw=(row&7)<<3;
      eA[cm] = __builtin_bit_cast(bf16x8, *reinterpret_cast<const u16x8*>(tile + row*64 + ((     lg*8)^sw)));
      vB[cm] = __builtin_bit_cast(bf16x8, *reinterpret_cast<const u16x8*>(tile + row*64 + ((32 + lg*8)^sw)));
    }
    #pragma unroll
    for (int cm=0; cm<4; ++cm)
      #pragma unroll
      for (int jn=0; jn<4; ++jn)
        acc[cm][jn] = mfma16(eA[cm], vB[jn], acc[cm][jn]);
  }

  // ---- all tile reads done: safe to alias tiles as reduction buffers ----
  __syncthreads();
  #pragma unroll
  for (int ct=0; ct<4; ++ct){
    float s = sume[ct];
    s += __shfl_xor(s,16,64); s += __shfl_xor(s,32,64);
    if (lg==0) ssum_l[wid*64 + ct*16+l15] = s;
  }
  #define CTX_RED(OP) \
    _Pragma("unroll") for (int cm=0;cm<4;++cm) \
    _Pragma("unroll") for (int jn=0;jn<4;++jn) \
    _Pragma("unroll") for (int r=0;r<4;++r) \
      ctx_l[(cm*16+lg*4+r)*68 + jn*16+l15] OP acc[cm][jn][r];
  if (wid==0){ CTX_RED(=) }  __syncthreads();
  if (wid==1){ CTX_RED(+=) } __syncthreads();
  if (wid==2){ CTX_RED(+=) } __syncthreads();
  if (wid==3){ CTX_RED(+=) } __syncthreads();
  #undef CTX_RED
  for (int i=t; i<4096; i+=256)
    g_part[(size_t)blockIdx.x*4096 + i] = ctx_l[(i>>6)*68 + (i&63)];
  if (t<64)
    g_sump[blockIdx.x*64 + t] = ssum_l[t] + ssum_l[64+t] + ssum_l[128+t] + ssum_l[192+t];
}

// ============ k15: reduce 64 partials/img; ctxWr = (ctx_norm @ Wr^T) -> bf16 frags ============
__global__ __launch_bounds__(512) void k15_ctxwr(
  const float* __restrict__ g_part, const float* __restrict__ g_sump,
  const float* __restrict__ Wr, unsigned short* __restrict__ ctxWrF)
{
  __shared__ float sctx[4096];
  __shared__ float sWr[4096];
  __shared__ float sinv[64];
  const int b = blockIdx.x, t = threadIdx.x;
  if (t<64){
    float s=0.f;
    #pragma unroll 8
    for (int p=0;p<64;++p) s += g_sump[(b*64+p)*64 + t];
    sinv[t] = 1.f/s;
  }
  for (int idx=t; idx<4096; idx+=512){
    float s=0.f;
    #pragma unroll 8
    for (int p=0;p<64;++p) s += g_part[(size_t)(b*64+p)*4096 + idx];
    sctx[idx] = s;
  }
  __syncthreads();
  {
    int c = t>>3, d0 = (t&7)*8;
    float invc = sinv[c];
    #pragma unroll
    for (int dd=0; dd<8; ++dd){
      int d = d0+dd; float s = 0.f;
      #pragma unroll
      for (int v=0; v<64; ++v) s += sctx[c*64+v]*Wr[d*64+v];
      sWr[c*64+d] = s*invc;
    }
  }
  __syncthreads();
  {
    int f = t>>6, l = t&63, nt = f>>1, ks = f&1;
    u16x8 v;
    #pragma unroll
    for (int j=0;j<8;++j){
      int k = ks*32 + (l>>4)*8 + j;
      int n = nt*16 + (l&15);
      v[j] = f2bf(sWr[k*64+n]);
    }
    *reinterpret_cast<u16x8*>(ctxWrF + b*4096 + f*512 + l*8) = v;
  }
}

// ============ k2: LN1 + q-softmax + attn + residual + LN2 + W1 -> fp8 g_h ============
__global__ __launch_bounds__(256,2) void k2_attn_ffn1(
  const float* __restrict__ x,
  const float* __restrict__ g1, const float* __restrict__ be1,
  const float* __restrict__ bq, const float* __restrict__ br,
  const float* __restrict__ g2, const float* __restrict__ be2,
  const float* __restrict__ b1,
  const unsigned short* __restrict__ wf,
  const unsigned short* __restrict__ ctxWrF,
  unsigned short* __restrict__ g_txb, unsigned char* __restrict__ g_h)
{
  __shared__ unsigned short tiles[4][4096];
  const int t = threadIdx.x, wid = t>>6, l = t&63;
  const int l15 = l&15, lg = l>>4;
  unsigned short* tile = tiles[wid];
  const int tok0 = (blockIdx.x*4 + wid)*64;
  const int img  = blockIdx.x>>6;
  const int yrow = (tok0>>7)&127;
  const int xb   = tok0&127;
  const size_t hbase = ((size_t)(img*128 + yrow)*HPITCH + 1 + xb)*256;  // BYTES (fp8)

  bf16x8 WqF[8], CWF[8];
  #pragma unroll
  for (int f=0; f<8; ++f){
    WqF[f] = ldfrag_g(wf + 4096 + f*512 + l*8);
    CWF[f] = ldfrag_g(ctxWrF + img*4096 + f*512 + l*8);
  }
  float4 g1v  = *reinterpret_cast<const float4*>(&g1[l15*4]);
  float4 be1v = *reinterpret_cast<const float4*>(&be1[l15*4]);
  float bqv[4], brv[4], g2v[4], be2v[4];
  #pragma unroll
  for (int nt=0; nt<4; ++nt){
    bqv[nt]=bq[nt*16+l15]; brv[nt]=br[nt*16+l15];
    g2v[nt]=g2[nt*16+l15]; be2v[nt]=be2[nt*16+l15];
  }
  float b1v[16];
  #pragma unroll
  for (int i=0;i<16;++i) b1v[i]=b1[i*16+l15];

  // ---- LN1 -> swizzled bf16 tile ----
  #pragma unroll
  for (int it=0; it<16; ++it){
    int row = it*4 + lg;
    float4 xv = *reinterpret_cast<const float4*>(&x[(size_t)(tok0+row)*64 + l15*4]);
    float s1 = xv.x+xv.y+xv.z+xv.w;
    float s2 = xv.x*xv.x + xv.y*xv.y + xv.z*xv.z + xv.w*xv.w;
    #pragma unroll
    for (int off=1; off<16; off<<=1){ s1 += __shfl_xor(s1,off,64); s2 += __shfl_xor(s2,off,64); }
    float mu = s1*(1.f/64.f);
    float rs = rsqrtf(s2*(1.f/64.f) - mu*mu + 1e-5f);
    uint2 pk = { pack2((xv.x-mu)*rs*g1v.x + be1v.x, (xv.y-mu)*rs*g1v.y + be1v.y),
                 pack2((xv.z-mu)*rs*g1v.z + be1v.z, (xv.w-mu)*rs*g1v.w + be1v.w) };
    *reinterpret_cast<uint2*>(&tile[row*64 + ((l15*4) ^ ((row&7)<<3))]) = pk;
  }

  // ---- phase A: per m-tile attn chain; leaves n2 in the tile ----
  for (int mt=0; mt<4; ++mt){
    const int arow = mt*16 + l15;
    const int asw  = (arow&7)<<3;
    const int abase= arow*64;
    bf16x8 a0 = __builtin_bit_cast(bf16x8, *reinterpret_cast<const u16x8*>(tile + abase + ((     lg*8) ^ asw)));
    bf16x8 a1 = __builtin_bit_cast(bf16x8, *reinterpret_cast<const u16x8*>(tile + abase + ((32 + lg*8) ^ asw)));
    f32x4 qa[4];
    #pragma unroll
    for (int nt=0; nt<4; ++nt){
      f32x4 z = {0.f,0.f,0.f,0.f};
      z = mfma16(a0, WqF[nt*2+0], z);
      z = mfma16(a1, WqF[nt*2+1], z);
      qa[nt] = z;
    }
    #pragma unroll
    for (int nt=0; nt<4; ++nt)
      #pragma unroll
      for (int r=0; r<4; ++r) qa[nt][r] += bqv[nt];
    float mx[4];
    #pragma unroll
    for (int r=0;r<4;++r) mx[r] = fmaxf(fmaxf(qa[0][r],qa[1][r]), fmaxf(qa[2][r],qa[3][r]));
    #pragma unroll
    for (int off=1; off<16; off<<=1)
      #pragma unroll
      for (int r=0;r<4;++r) mx[r] = fmaxf(mx[r], __shfl_xor(mx[r], off, 64));
    float sm[4] = {0.f,0.f,0.f,0.f};
    #pragma unroll
    for (int nt=0;nt<4;++nt)
      #pragma unroll
      for (int r=0;r<4;++r){ float e = __expf(qa[nt][r]-mx[r]); qa[nt][r]=e; sm[r]+=e; }
    #pragma unroll
    for (int off=1; off<16; off<<=1)
      #pragma unroll
      for (int r=0;r<4;++r) sm[r] += __shfl_xor(sm[r], off, 64);
    float inv[4];
    #pragma unroll
    for (int r=0;r<4;++r) inv[r] = 1.f/sm[r];
    #pragma unroll
    for (int nt=0;nt<4;++nt)
      #pragma unroll
      for (int r=0;r<4;++r){
        int row = mt*16 + lg*4 + r, col = nt*16 + l15;
        tile[row*64 + (col ^ ((row&7)<<3))] = f2bf(qa[nt][r]*inv[r]);
      }
    bf16x8 p0 = __builtin_bit_cast(bf16x8, *reinterpret_cast<const u16x8*>(tile + abase + ((     lg*8) ^ asw)));
    bf16x8 p1 = __builtin_bit_cast(bf16x8, *reinterpret_cast<const u16x8*>(tile + abase + ((32 + lg*8) ^ asw)));
    f32x4 ao[4];
    #pragma unroll
    for (int nt=0; nt<4; ++nt){
      f32x4 z = {0.f,0.f,0.f,0.f};
      z = mfma16(p0, CWF[nt*2+0], z);
      z = mfma16(p1, CWF[nt*2+1], z);
      ao[nt] = z;
    }
    float txv[4][4];
    float s1v[4] = {0.f,0.f,0.f,0.f}, s2v[4] = {0.f,0.f,0.f,0.f};
    #pragma unroll
    for (int nt=0;nt<4;++nt)
      #pragma unroll
      for (int r=0;r<4;++r){
        size_t row = (size_t)(tok0 + mt*16 + lg*4 + r);
        float v = ao[nt][r] + brv[nt] + x[row*64 + nt*16+l15];
        g_txb[row*64 + nt*16+l15] = f2bf(v);
        txv[nt][r] = v; s1v[r] += v; s2v[r] += v*v;
      }
    #pragma unroll
    for (int off=1; off<16; off<<=1)
      #pragma unroll
      for (int r=0;r<4;++r){ s1v[r] += __shfl_xor(s1v[r], off, 64); s2v[r] += __shfl_xor(s2v[r], off, 64); }
    #pragma unroll
    for (int r=0;r<4;++r){
      float mu2 = s1v[r]*(1.f/64.f);
      float rs  = rsqrtf(s2v[r]*(1.f/64.f) - mu2*mu2 + 1e-5f);
      s1v[r] = mu2; s2v[r] = rs;
    }
    #pragma unroll
    for (int nt=0;nt<4;++nt)
      #pragma unroll
      for (int r=0;r<4;++r){
        int row = mt*16 + lg*4 + r, col = nt*16 + l15;
        float n2 = (txv[nt][r]-s1v[r])*s2v[r]*g2v[nt] + be2v[nt];
        tile[row*64 + (col ^ ((row&7)<<3))] = f2bf(n2);
      }
  }

  // ---- phase B: h = n2 @ W1^T + b1; mt-outer, fp8-packed PERMUTED uint4 stores ----
  // channel c = nt2*16 + l15 stored at slot c' = l15*16 + nt2  => 16 contiguous fp8/thread/row.
  for (int mt=0; mt<4; ++mt){
    const int arow = mt*16 + l15;
    const int asw  = (arow&7)<<3;
    const int abase= arow*64;
    bf16x8 n20 = __builtin_bit_cast(bf16x8, *reinterpret_cast<const u16x8*>(tile + abase + ((     lg*8) ^ asw)));
    bf16x8 n21 = __builtin_bit_cast(bf16x8, *reinterpret_cast<const u16x8*>(tile + abase + ((32 + lg*8) ^ asw)));
    unsigned hq[4][4];
    #pragma unroll
    for (int np=0; np<8; ++np){
      bf16x8 wa0 = ldfrag_g(wf + 16384 + (np*4+0)*512 + l*8);
      bf16x8 wa1 = ldfrag_g(wf + 16384 + (np*4+1)*512 + l*8);
      bf16x8 wb0 = ldfrag_g(wf + 16384 + (np*4+2)*512 + l*8);
      bf16x8 wb1 = ldfrag_g(wf + 16384 + (np*4+3)*512 + l*8);
      float ba = b1v[np*2], bb = b1v[np*2+1];
      f32x4 ha = {ba,ba,ba,ba};
      ha = mfma16(n20, wa0, ha);
      ha = mfma16(n21, wa1, ha);
      f32x4 hb = {bb,bb,bb,bb};
      hb = mfma16(n20, wb0, hb);
      hb = mfma16(n21, wb1, hb);
      const int d = np>>1;
      if ((np&1)==0){
        #pragma unroll
        for (int r=0;r<4;++r)
          hq[r][d] = (unsigned)__builtin_amdgcn_cvt_pk_fp8_f32(ha[r], hb[r], 0, false);
      } else {
        #pragma unroll
        for (int r=0;r<4;++r)
          hq[r][d] = (unsigned)__builtin_amdgcn_cvt_pk_fp8_f32(ha[r], hb[r], (int)hq[r][d], true);
      }
    }
    #pragma unroll
    for (int r=0;r<4;++r){
      const size_t ro = hbase + (size_t)(mt*16+lg*4+r)*256 + l15*16;
      uint4 v = { hq[r][0], hq[r][1], hq[r][2], hq[r][3] };
      *reinterpret_cast<uint4*>(g_h + ro) = v;
    }
  }
}

// ============ k3: depthwise conv3x3 + GELU + W2 — fp8 ring, 2ch/lane packed conv ============
__global__ __launch_bounds__(256,4) void k3_conv_ffn2(
  const unsigned char* __restrict__ g_h,
  const unsigned char* __restrict__ zrow,
  const float* __restrict__ dwp,
  const float* __restrict__ b2,
  const unsigned short* __restrict__ wf,
  const unsigned short* __restrict__ g_txb, float* __restrict__ out)
{
  __shared__ unsigned ring[4][1170];        // 4 slots x 18 pos x 65-dword pitch = 18.7 KB
  __shared__ unsigned short obuf[2][4096];  // double-buffered 16tok x 256ch = 16 KB
  const int t = threadIdx.x, w = t>>6, l = t&63;
  const int l15 = l&15, lg = l>>4;
  const int bid = (blockIdx.x & 7)*128 + (blockIdx.x >> 3);   // XCD-chunked remap
  const int img = bid>>6;
  const int r6  = bid&63;
  const int y0  = (r6>>3)*16, x0 = (r6&7)*16;

  // conv: lane's channel pair cp (slots 2cp, 2cp+1); position group pg
  const int cp = t & 127;
  const int pg = t >> 7;
  f32x2 tp[9];
  #pragma unroll
  for (int j=0;j<9;++j)
    tp[j] = *reinterpret_cast<const f32x2*>(&dwp[cp*24 + j*2]);
  const f32x2 cb2 = *reinterpret_cast<const f32x2*>(&dwp[cp*24 + 18]);

  // W2 frags for output quarter ntc = w
  bf16x8 W2F[8];
  #pragma unroll
  for (int q=0;q<8;++q)
    W2F[q] = ldfrag_g(wf + 32768 + (w*8 + q)*512 + l*8);
  const float4 b2q = *reinterpret_cast<const float4*>(&b2[w*16 + lg*4]);

  // staging map: thread t stages position pi = 1+(t>>4), channels c0..c0+15
  const int pi = 1 + (t>>4);
  const int c0 = (t&15)*16;

  auto rowsrc = [&](int ri) -> const unsigned char* {
    return (ri>=0 && ri<128)
      ? g_h + ((size_t)(img*128+ri)*HPITCH + x0)*256
      : zrow + x0*256;
  };
  auto ldrow = [&](int ri, uint4* m, unsigned* h){
    const unsigned char* src = rowsrc(ri);
    *m = *reinterpret_cast<const uint4*>(src + pi*256 + c0);
    if (t < 128){
      int ph = (t<64)?0:17, dh = t&63;
      *h = reinterpret_cast<const unsigned*>(src + ph*256)[dh];
    }
  };
  auto wrrow = [&](int sl, uint4 m, unsigned h){
    unsigned* rg = ring[sl];
    const int base = pi*65 + (c0>>2);
    rg[base+0] = m.x; rg[base+1] = m.y; rg[base+2] = m.z; rg[base+3] = m.w;
    if (t < 128){
      int ph = (t<64)?0:17, dh = t&63;
      rg[ph*65 + dh] = h;
    }
  };

  // prologue: stage rows y0-1, y0, y0+1 into slots 0,1,2
  {
    uint4 m0,m1,m2; unsigned h0=0,h1=0,h2=0;
    ldrow(y0-1,&m0,&h0); ldrow(y0,&m1,&h1); ldrow(y0+1,&m2,&h2);
    wrrow(0,m0,h0); wrrow(1,m1,h1); wrrow(2,m2,h2);
  }
  __syncthreads();

  const f32x2 kC0 = {-2.3022082f,-2.3022082f};
  const f32x2 kC1 = {-0.1029432f,-0.1029432f};

  for (int yy=0; yy<16; ++yy){
    const int gy = y0 + yy;
    // T14 issue-early: fp8 loads of row gy+2 into regs
    uint4 rm; unsigned rh = 0;
    ldrow(gy+2, &rm, &rh);
    // epilogue residual prefetch
    const size_t gtok = (size_t)img*16384 + (size_t)gy*128 + x0 + l15;
    const u16x4v tq = *reinterpret_cast<const u16x4v*>(&g_txb[gtok*64 + w*16 + lg*4]);

    // conv from fp8 ring (rows y-1,y,y+1 = slots yy, yy+1, yy+2 mod 4)
    {
      const unsigned short* rA = reinterpret_cast<const unsigned short*>(ring[(yy  )&3]);
      const unsigned short* rB = reinterpret_cast<const unsigned short*>(ring[(yy+1)&3]);
      const unsigned short* rC = reinterpret_cast<const unsigned short*>(ring[(yy+2)&3]);
      unsigned short* ob = obuf[yy&1];
      const int rb = pg*8;
      f32x2 PA = __builtin_amdgcn_cvt_pk_f32_fp8((int)rA[(rb  )*130 + cp], false);
      f32x2 PB = __builtin_amdgcn_cvt_pk_f32_fp8((int)rB[(rb  )*130 + cp], false);
      f32x2 PC = __builtin_amdgcn_cvt_pk_f32_fp8((int)rC[(rb  )*130 + cp], false);
      f32x2 CA = __builtin_amdgcn_cvt_pk_f32_fp8((int)rA[(rb+1)*130 + cp], false);
      f32x2 CB = __builtin_amdgcn_cvt_pk_f32_fp8((int)rB[(rb+1)*130 + cp], false);
      f32x2 CC = __builtin_amdgcn_cvt_pk_f32_fp8((int)rC[(rb+1)*130 + cp], false);
      #pragma unroll
      for (int i=0;i<8;++i){
        const int ro = (rb+i+2)*130 + cp;
        f32x2 NA = __builtin_amdgcn_cvt_pk_f32_fp8((int)rA[ro], false);
        f32x2 NB = __builtin_amdgcn_cvt_pk_f32_fp8((int)rB[ro], false);
        f32x2 NC = __builtin_amdgcn_cvt_pk_f32_fp8((int)rC[ro], false);
        f32x2 a = cb2;
        a += tp[0]*PA; a += tp[1]*CA; a += tp[2]*NA;
        a += tp[3]*PB; a += tp[4]*CB; a += tp[5]*NB;
        a += tp[6]*PC; a += tp[7]*CC; a += tp[8]*NC;
        f32x2 u = a*a;
        f32x2 wv = u*kC1 + kC0;
        f32x2 arg = a*wv;
        f32x2 e;
        e[0]=__builtin_amdgcn_exp2f(arg[0]); e[1]=__builtin_amdgcn_exp2f(arg[1]);
        f32x2 den = e + (f32x2){1.f,1.f};
        f32x2 rc;
        rc[0]=__builtin_amdgcn_rcpf(den[0]); rc[1]=__builtin_amdgcn_rcpf(den[1]);
        f32x2 g = a*rc;
        unsigned pk;
        asm("v_cvt_pk_bf16_f32 %0, %1, %2" : "=v"(pk) : "v"(g[0]), "v"(g[1]));
        const int p = rb + i;
        *reinterpret_cast<unsigned*>(&ob[p*256 + ((2*cp) ^ ((p&7)<<3))]) = pk;
        PA=CA; PB=CB; PC=CC; CA=NA; CB=NB; CC=NC;
      }
    }

    // write-late: staged fp8 row -> ring slot (yy+3)&3 (raw dwords)
    wrrow((yy+3)&3, rm, rh);
    __syncthreads();

    // W2 MFMA: wave w computes output quarter w over K=256
    f32x4 oacc = {0.f,0.f,0.f,0.f};
    const int nsw = (l15&7)<<3;
    const unsigned short* ob = obuf[yy&1];
    #pragma unroll
    for (int i=0;i<4;++i){
      bf16x8 fb0 = __builtin_bit_cast(bf16x8,
        *reinterpret_cast<const u16x8*>(&ob[l15*256 + ((i*64      + lg*8) ^ nsw)]));
      bf16x8 fb1 = __builtin_bit_cast(bf16x8,
        *reinterpret_cast<const u16x8*>(&ob[l15*256 + ((i*64 + 32 + lg*8) ^ nsw)]));
      oacc = mfma16(W2F[i*2+0], fb0, oacc);
      oacc = mfma16(W2F[i*2+1], fb1, oacc);
    }
    float4 o;
    o.x = oacc[0] + b2q.x + bf2f(tq[0]);
    o.y = oacc[1] + b2q.y + bf2f(tq[1]);
    o.z = oacc[2] + b2q.z + bf2f(tq[2]);
    o.w = oacc[3] + b2q.w + bf2f(tq[3]);
    *reinterpret_cast<float4*>(&out[gtok*64 + w*16 + lg*4]) = o;
  }
}

extern "C" void kernel_launch(void* const* d_in, const int* in_sizes, int n_in,
                              void* d_out, int out_size, void* d_ws, size_t ws_size,
                              hipStream_t stream)
{
  const float* x  =(const float*)d_in[0];
  const float* g1 =(const float*)d_in[3];
  const float* be1=(const float*)d_in[4];
  const float* Wk =(const float*)d_in[5];
  const float* bk =(const float*)d_in[6];
  const float* Wq =(const float*)d_in[7];
  const float* bq =(const float*)d_in[8];
  const float* Wv =(const float*)d_in[9];
  const float* bv =(const float*)d_in[10];
  const float* Wr =(const float*)d_in[11];
  const float* br =(const float*)d_in[12];
  const float* g2 =(const float*)d_in[13];
  const float* be2=(const float*)d_in[14];
  const float* W1 =(const float*)d_in[15];
  const float* b1 =(const float*)d_in[16];
  const float* dww=(const float*)d_in[17];
  const float* dwb=(const float*)d_in[18];
  const float* W2 =(const float*)d_in[19];
  const float* b2 =(const float*)d_in[20];
  float* outp = (float*)d_out;
  char* ws = (char*)d_ws;

  unsigned short* wfb    = (unsigned short*)ws;                 // 96KB
  unsigned short* ctxWrF = (unsigned short*)(ws + 98304);       // 128KB
  float* g_sump = (float*)(ws + 229376);                        // 256KB (1024x64 f32)
  float* g_part = (float*)(ws + 524288);                        // 16.78MB (1024x4096 f32)
  unsigned short* g_txb = (unsigned short*)(ws + 17825792);     // 32MB bf16
  unsigned char* g_h    = (unsigned char*)(ws + 51380224);      // 68.2MB padded fp8
  unsigned char* zr     = (unsigned char*)(ws + 119537664);     // 33KB fp8 zero row
  float* dwp            = (float*)(ws + 119603200);             // 12KB repacked taps+bias

  hipLaunchKernelGGL(k0_wfrag, dim3(97), dim3(64), 0, stream, Wk, Wq, Wv, Wr, W1, W2, dww, dwb, dwp, wfb);
  hipLaunchKernelGGL(zhalo, dim3(1057), dim3(256), 0, stream, (unsigned*)g_h, (unsigned*)zr);
  hipLaunchKernelGGL(k1_ctx, dim3(1024), dim3(256), 0, stream, x, g1, be1, bk, bv, wfb, g_part, g_sump);
  hipLaunchKernelGGL(k15_ctxwr, dim3(16), dim3(512), 0, stream, g_part, g_sump, Wr, ctxWrF);
  hipLaunchKernelGGL(k2_attn_ffn1, dim3(1024), dim3(256), 0, stream,
                     x, g1, be1, bq, br, g2, be2, b1, wfb, ctxWrF, g_txb, g_h);
  hipLaunchKernelGGL(k3_conv_ffn2, dim3(1024), dim3(256), 0, stream,
                     g_h, zr, dwp, b2, wfb, g_txb, outp);
}